// Round 3
// baseline (948.754 us; speedup 1.0000x reference)
//
#include <hip/hip_runtime.h>

#define N_NODES 100000
#define N_EDGES 1600000
#define IN_DIM 128
#define H1_DIM 64
#define H2_DIM 32
#define OUT_DIM 16

#define NPB 64                                    // src-nodes per bucket
#define KB ((N_NODES + NPB - 1) / NPB)            // 1563 buckets
#define CAP 1536                                  // per-bucket cap (mean 1024, sigma 32)
#define U 8                                       // gather unroll (independent chains)

// ---------------- prep: Wc = W2@W1 [32x128], cvec = W2@b1 [32] ----------------
__global__ void prep_kernel(const float* __restrict__ W1, const float* __restrict__ b1,
                            const float* __restrict__ W2,
                            float* __restrict__ Wc, float* __restrict__ cvec) {
    int t = threadIdx.x;  // 256 threads, 1 block
    for (int idx = t; idx < H2_DIM * IN_DIM; idx += 256) {
        int j = idx >> 7, f = idx & 127;
        float acc = 0.f;
        for (int k = 0; k < H1_DIM; ++k)
            acc += W2[j * H1_DIM + k] * W1[k * IN_DIM + f];
        Wc[idx] = acc;
    }
    if (t < H2_DIM) {
        float acc = 0.f;
        for (int k = 0; k < H1_DIM; ++k)
            acc += W2[t * H1_DIM + k] * b1[k];
        cvec[t] = acc;
    }
}

// ---------------- y = x @ Wc^T  [N,32] ----------------
__global__ __launch_bounds__(256) void gemmy_kernel(const float* __restrict__ x,
                                                    const float* __restrict__ Wc,
                                                    float* __restrict__ y) {
    __shared__ float wl[H2_DIM * 129];
    int t = threadIdx.x;
    for (int idx = t; idx < H2_DIM * IN_DIM; idx += 256) {
        int j = idx >> 7, f = idx & 127;
        wl[j * 129 + f] = Wc[idx];
    }
    __syncthreads();
    int g = t >> 5, j = t & 31;
    int i = blockIdx.x * 8 + g;
    if (i >= N_NODES) return;
    const float4* xr = (const float4*)(x + (size_t)i * IN_DIM);
    const float* wrow = wl + j * 129;
    float acc = 0.f;
#pragma unroll
    for (int k4 = 0; k4 < 32; ++k4) {
        float4 v = xr[k4];
        acc += v.x * wrow[4 * k4] + v.y * wrow[4 * k4 + 1] +
               v.z * wrow[4 * k4 + 2] + v.w * wrow[4 * k4 + 3];
    }
    y[(size_t)i * H2_DIM + j] = acc;
}

// ---------------- bin: bucketed scatter of packed records ---------------------
// Cursor working set = KB cache lines (~100 KB) -> L2-resident, low write-amp.
__global__ __launch_bounds__(256) void bin_kernel(const int* __restrict__ src,
                                                  const int* __restrict__ dst,
                                                  int* __restrict__ gcur,
                                                  unsigned* __restrict__ grec) {
    int e = blockIdx.x * blockDim.x + threadIdx.x;
    int stride = gridDim.x * blockDim.x;
    for (; e < N_EDGES; e += stride) {
        int s = src[e];
        int d = dst[e];
        int b = s >> 6;
        int p = atomicAdd(&gcur[b], 1);
        if (p < CAP)
            grec[(size_t)b * CAP + p] = ((unsigned)(s & 63) << 17) | (unsigned)d;
    }
}

// ---------------- key encode for float atomicMax ------------------------------
__device__ inline unsigned f32_to_key(float v) {
    unsigned u = __float_as_uint(v);
    return (v >= 0.f) ? (u | 0x80000000u) : ~u;
}

// ---------------- agg: per-bucket LDS accumulate ------------------------------
// ROUND 1: outz[node] = sum in[dst]
// ROUND 2: fused finalize -> column max of (acc + deg*c + b2) into pk
//          (deg re-counted in LDS from the same records)
template <int ROUND>
__global__ __launch_bounds__(256) void agg_kernel(const float* __restrict__ in,
                                                  const unsigned* __restrict__ grec,
                                                  const int* __restrict__ gcur,
                                                  float* __restrict__ outz,
                                                  const float* __restrict__ cvec,
                                                  const float* __restrict__ b2,
                                                  unsigned* __restrict__ pk) {
    __shared__ float acc[NPB * 33];
    __shared__ int dacc[NPB];
    __shared__ float sm[256];
    int t = threadIdx.x;
    int b = blockIdx.x;
    for (int i = t; i < NPB * 33; i += 256) acc[i] = 0.f;
    if (ROUND == 2)
        for (int i = t; i < NPB; i += 256) dacc[i] = 0;
    __syncthreads();

    int cnt = min(gcur[b], CAP);
    int base = b * CAP;
    int g = t >> 5, f = t & 31;
    for (int r0 = g * U; r0 < cnt; r0 += 8 * U) {
        unsigned rc[U];
        float vv[U];
        int ok[U];
#pragma unroll
        for (int k = 0; k < U; ++k) {
            int r = r0 + k;
            ok[k] = (r < cnt);
            rc[k] = ok[k] ? grec[base + r] : 0u;
        }
#pragma unroll
        for (int k = 0; k < U; ++k) {
            int d = (int)(rc[k] & 0x1FFFFu);
            vv[k] = ok[k] ? in[(size_t)d * H2_DIM + f] : 0.f;
        }
#pragma unroll
        for (int k = 0; k < U; ++k) {
            if (ok[k]) {
                int sl = (int)(rc[k] >> 17);
                __hip_atomic_fetch_add(&acc[sl * 33 + f], vv[k],
                                       __ATOMIC_RELAXED, __HIP_MEMORY_SCOPE_WORKGROUP);
                if (ROUND == 2 && f == 0) atomicAdd(&dacc[sl], 1);
            }
        }
    }
    __syncthreads();

    if (ROUND == 1) {
        for (int idx = t; idx < NPB * H2_DIM; idx += 256) {
            int sl = idx >> 5, ff = idx & 31;
            int node = b * NPB + sl;
            if (node < N_NODES)
                outz[(size_t)node * H2_DIM + ff] = acc[sl * 33 + ff];
        }
    } else {
        float c = cvec[f], bb = b2[f];
        float m = -3.402823466e+38f;
        for (int idx = t; idx < NPB * H2_DIM; idx += 256) {
            int sl = idx >> 5;  // lane's f is constant since 256 % 32 == 0
            int node = b * NPB + sl;
            if (node < N_NODES) {
                float v = acc[sl * 33 + f] + (float)dacc[sl] * c + bb;
                m = fmaxf(m, v);
            }
        }
        sm[t] = m;
        __syncthreads();
        if (g == 0) {
#pragma unroll
            for (int k = 1; k < 8; ++k) m = fmaxf(m, sm[k * 32 + f]);
            atomicMax(&pk[f], f32_to_key(m));
        }
    }
}

// ---------------- out = pooled @ Wf^T + bf ----------------
__global__ void final_kernel(const unsigned* __restrict__ pk,
                             const float* __restrict__ Wf,
                             const float* __restrict__ bfv,
                             float* __restrict__ out) {
    __shared__ float pooled[H2_DIM];
    int t = threadIdx.x;
    if (t < H2_DIM) {
        unsigned k = pk[t];
        unsigned u = (k & 0x80000000u) ? (k & 0x7FFFFFFFu) : ~k;
        pooled[t] = __uint_as_float(u);
    }
    __syncthreads();
    if (t < OUT_DIM) {
        float acc = bfv[t];
        for (int j = 0; j < H2_DIM; ++j)
            acc += Wf[t * H2_DIM + j] * pooled[j];
        out[t] = acc;
    }
}

extern "C" void kernel_launch(void* const* d_in, const int* in_sizes, int n_in,
                              void* d_out, int out_size, void* d_ws, size_t ws_size,
                              hipStream_t stream) {
    const float* x  = (const float*)d_in[0];
    const int*   ei = (const int*)d_in[1];           // [2, E]: row0 = src, row1 = dst
    const float* W1 = (const float*)d_in[2];
    const float* b1 = (const float*)d_in[3];
    const float* W2 = (const float*)d_in[4];
    const float* b2 = (const float*)d_in[5];
    const float* Wf = (const float*)d_in[6];
    const float* bf = (const float*)d_in[7];
    float* out = (float*)d_out;

    const int* src = ei;
    const int* dst = ei + N_EDGES;

    // workspace carve-up (~35 MB)
    float* y    = (float*)d_ws;                      // N*32
    float* z1   = y + (size_t)N_NODES * H2_DIM;      // N*32
    float* Wc   = z1 + (size_t)N_NODES * H2_DIM;     // 32*128
    float* cvec = Wc + H2_DIM * IN_DIM;              // 32
    int*   gcur = (int*)(cvec + H2_DIM);             // KB
    unsigned* pk = (unsigned*)(gcur + KB);           // 32
    unsigned* grec = pk + H2_DIM;                    // KB*CAP (~9.6 MB)

    hipMemsetAsync(gcur, 0, KB * sizeof(int), stream);
    hipMemsetAsync(pk, 0, H2_DIM * sizeof(unsigned), stream);

    prep_kernel<<<1, 256, 0, stream>>>(W1, b1, W2, Wc, cvec);
    gemmy_kernel<<<(N_NODES + 7) / 8, 256, 0, stream>>>(x, Wc, y);
    bin_kernel<<<2048, 256, 0, stream>>>(src, dst, gcur, grec);

    agg_kernel<1><<<KB, 256, 0, stream>>>(y, grec, gcur, z1, cvec, b2, pk);
    agg_kernel<2><<<KB, 256, 0, stream>>>(z1, grec, gcur, nullptr, cvec, b2, pk);

    final_kernel<<<1, 64, 0, stream>>>(pk, Wf, bf, out);
}

// Round 4
// 193.094 us; speedup vs baseline: 4.9134x; 4.9134x over previous
//
#include <hip/hip_runtime.h>

#define N_NODES 100000
#define N_EDGES 1600000
#define IN_DIM 128
#define H1_DIM 64
#define H2_DIM 32
#define OUT_DIM 16

#define NPB 64                       // src-nodes per bucket
#define KB 1563                      // ceil(N_NODES / NPB)
#define OFFW (KB + 1)                // off-table row width (with sentinel)
#define NCH 128                      // edge chunks (private regions)
#define CH_E (N_EDGES / NCH)         // 12500 edges per chunk (exact)
#define CAP2 1536                    // per-bucket record cap (mean 1024, +16 sigma)

// ---------------- helpers ----------------
__device__ inline float b2f(unsigned short h) {
    return __uint_as_float(((unsigned)h) << 16);
}
__device__ inline unsigned short f2b(float v) {   // RNE f32 -> bf16
    unsigned u = __float_as_uint(v);
    u += 0x7FFF + ((u >> 16) & 1);
    return (unsigned short)(u >> 16);
}
__device__ inline unsigned f32_to_key(float v) {
    unsigned u = __float_as_uint(v);
    return (v >= 0.f) ? (u | 0x80000000u) : ~u;
}

// ---------------- prep: Wc = W2@W1 [32x128], cvec = W2@b1 [32] ----------------
__global__ void prep_kernel(const float* __restrict__ W1, const float* __restrict__ b1,
                            const float* __restrict__ W2,
                            float* __restrict__ Wc, float* __restrict__ cvec) {
    int t = threadIdx.x;  // 256 threads, 1 block
    for (int idx = t; idx < H2_DIM * IN_DIM; idx += 256) {
        int j = idx >> 7, f = idx & 127;
        float acc = 0.f;
        for (int k = 0; k < H1_DIM; ++k)
            acc += W2[j * H1_DIM + k] * W1[k * IN_DIM + f];
        Wc[idx] = acc;
    }
    if (t < H2_DIM) {
        float acc = 0.f;
        for (int k = 0; k < H1_DIM; ++k)
            acc += W2[t * H1_DIM + k] * b1[k];
        cvec[t] = acc;
    }
}

// ---------------- y = x @ Wc^T  [N,32] -> bf16 ----------------
__global__ __launch_bounds__(256) void gemmy_kernel(const float* __restrict__ x,
                                                    const float* __restrict__ Wc,
                                                    unsigned short* __restrict__ yb) {
    __shared__ float wl[H2_DIM * 129];
    int t = threadIdx.x;
    for (int idx = t; idx < H2_DIM * IN_DIM; idx += 256) {
        int j = idx >> 7, f = idx & 127;
        wl[j * 129 + f] = Wc[idx];
    }
    __syncthreads();
    int g = t >> 5, j = t & 31;
    int i = blockIdx.x * 8 + g;
    if (i >= N_NODES) return;
    const float4* xr = (const float4*)(x + (size_t)i * IN_DIM);
    const float* wrow = wl + j * 129;
    float acc = 0.f;
#pragma unroll
    for (int k4 = 0; k4 < 32; ++k4) {
        float4 v = xr[k4];
        acc += v.x * wrow[4 * k4] + v.y * wrow[4 * k4 + 1] +
               v.z * wrow[4 * k4 + 2] + v.w * wrow[4 * k4 + 3];
    }
    yb[(size_t)i * H2_DIM + j] = f2b(acc);
}

// ---------------- bin: chunk-private bucket binning ---------------------------
// Each block owns edges [c*CH_E, (c+1)*CH_E) and region grec[c*CH_E ...].
// Records of a bucket land in consecutive private slots -> write-amp ~1.
__global__ __launch_bounds__(512) void bin_kernel(const int* __restrict__ src,
                                                  const int* __restrict__ dst,
                                                  unsigned* __restrict__ off,
                                                  unsigned* __restrict__ grec) {
    __shared__ int hist[2048];
    __shared__ int part[512];
    __shared__ int cur[2048];
    int t = threadIdx.x;
    int c = blockIdx.x;
    int e0 = c * CH_E;

    for (int i = t; i < 2048; i += 512) hist[i] = 0;
    __syncthreads();
    for (int e = t; e < CH_E; e += 512) {
        int s = src[e0 + e];
        atomicAdd(&hist[s >> 6], 1);
    }
    __syncthreads();
    int h0 = hist[4 * t], h1 = hist[4 * t + 1], h2 = hist[4 * t + 2], h3 = hist[4 * t + 3];
    int tot = h0 + h1 + h2 + h3;
    part[t] = tot;
    __syncthreads();
    for (int o = 1; o < 512; o <<= 1) {
        int a = (t >= o) ? part[t - o] : 0;
        __syncthreads();
        part[t] += a;
        __syncthreads();
    }
    int gb = part[t] - tot;  // exclusive prefix of this 4-group
    int o0 = gb, o1 = gb + h0, o2 = o1 + h1, o3 = o2 + h2;
    int b4 = 4 * t;
    if (b4 + 0 < KB) { off[(size_t)c * OFFW + b4 + 0] = o0; cur[b4 + 0] = o0; }
    if (b4 + 1 < KB) { off[(size_t)c * OFFW + b4 + 1] = o1; cur[b4 + 1] = o1; }
    if (b4 + 2 < KB) { off[(size_t)c * OFFW + b4 + 2] = o2; cur[b4 + 2] = o2; }
    if (b4 + 3 < KB) { off[(size_t)c * OFFW + b4 + 3] = o3; cur[b4 + 3] = o3; }
    if (t == 0) off[(size_t)c * OFFW + KB] = CH_E;   // sentinel
    __syncthreads();
    for (int e = t; e < CH_E; e += 512) {
        int s = src[e0 + e];
        int d = dst[e0 + e];
        int p = atomicAdd(&cur[s >> 6], 1);
        grec[(size_t)e0 + p] = ((unsigned)(s & 63) << 17) | (unsigned)d;
    }
}

// ---------------- agg: per-bucket node-sorted register-accum gather -----------
// ROUND 1: gather runs from 128 private regions, counting-sort by node in LDS,
//          persist sorted records (grec2) + per-node offsets (noff), gather y -> z1 (bf16)
// ROUND 2: reload sorted records, gather z1; fused (+deg*c+b2) and column max-pool.
template <int ROUND>
__global__ __launch_bounds__(256) void agg_kernel(const unsigned short* __restrict__ in,
                                                  const unsigned* __restrict__ off,
                                                  const unsigned* __restrict__ grec,
                                                  unsigned* __restrict__ grec2,
                                                  unsigned* __restrict__ noff,
                                                  unsigned short* __restrict__ z1b,
                                                  const float* __restrict__ cvec,
                                                  const float* __restrict__ b2,
                                                  unsigned* __restrict__ pk) {
    __shared__ int len[128], pos[128], sst[128];
    __shared__ int shist[64], scur[64];
    __shared__ int sscan[65];
    __shared__ unsigned rbuf[CAP2];
    __shared__ unsigned sbuf[CAP2];
    __shared__ float sm[256];
    __shared__ int s_cnt;
    int t = threadIdx.x;
    int b = blockIdx.x;
    int g = t >> 5, f = t & 31;

    if (ROUND == 1) {
        // run table from the 128 private regions
        if (t < 128) {
            unsigned o0 = off[(size_t)t * OFFW + b];
            unsigned o1 = off[(size_t)t * OFFW + b + 1];
            sst[t] = (int)o0;
            len[t] = (int)(o1 - o0);
            pos[t] = (int)(o1 - o0);
        }
        __syncthreads();
        for (int o = 1; o < 128; o <<= 1) {
            int a = (t < 128 && t >= o) ? pos[t - o] : 0;
            __syncthreads();
            if (t < 128) pos[t] += a;
            __syncthreads();
        }
        if (t < 128) pos[t] -= len[t];              // exclusive
        if (t == 127) s_cnt = min(pos[127] + len[127], CAP2);
        __syncthreads();
        // coalesced copy of runs into rbuf (group g takes regions g, g+8, ...)
        for (int c = g; c < 128; c += 8) {
            int L = len[c], P = pos[c], S = sst[c];
            for (int k = f; k < L; k += 32) {
                int q = P + k;
                if (q < CAP2) rbuf[q] = grec[(size_t)c * CH_E + S + k];
            }
        }
        // counting sort by local node id
        if (t < 64) shist[t] = 0;
        __syncthreads();
        int cnt = s_cnt;
        for (int i = t; i < cnt; i += 256) atomicAdd(&shist[rbuf[i] >> 17], 1);
        __syncthreads();
        if (t < 64) scur[t] = shist[t];
        __syncthreads();
        for (int o = 1; o < 64; o <<= 1) {
            int a = (t < 64 && t >= o) ? scur[t - o] : 0;
            __syncthreads();
            if (t < 64) scur[t] += a;
            __syncthreads();
        }
        if (t < 64) sscan[t] = scur[t] - shist[t];
        if (t == 63) sscan[64] = scur[63];
        __syncthreads();
        if (t < 64) scur[t] = sscan[t];
        __syncthreads();
        for (int i = t; i < cnt; i += 256) {
            unsigned r = rbuf[i];
            int p = atomicAdd(&scur[r >> 17], 1);
            if (p < CAP2) sbuf[p] = r;
        }
        __syncthreads();
        // persist for round 2
        for (int i = t; i < cnt; i += 256) grec2[(size_t)b * CAP2 + i] = sbuf[i];
        if (t < 65) noff[(size_t)b * 65 + t] = (unsigned)sscan[t];
    } else {
        if (t < 65) sscan[t] = (int)noff[(size_t)b * 65 + t];
        __syncthreads();
        int cnt = sscan[64];
        for (int i = t; i < cnt; i += 256) sbuf[i] = grec2[(size_t)b * CAP2 + i];
    }
    __syncthreads();

    // gather phase: group g handles nodes sl = g, g+8, ..., 56 (lane = feature f)
    float cf = 0.f, bb = 0.f, m = -3.402823466e+38f;
    if (ROUND == 2) { cf = cvec[f]; bb = b2[f]; }
    for (int sl = g; sl < 64; sl += 8) {
        int r0 = sscan[sl], r1 = sscan[sl + 1];
        float a0 = 0.f, a1 = 0.f, a2 = 0.f, a3 = 0.f;
        int e = r0;
        for (; e + 4 <= r1; e += 4) {
            unsigned q0 = sbuf[e], q1 = sbuf[e + 1], q2 = sbuf[e + 2], q3 = sbuf[e + 3];
            unsigned short v0 = in[(size_t)(q0 & 0x1FFFFu) * H2_DIM + f];
            unsigned short v1 = in[(size_t)(q1 & 0x1FFFFu) * H2_DIM + f];
            unsigned short v2 = in[(size_t)(q2 & 0x1FFFFu) * H2_DIM + f];
            unsigned short v3 = in[(size_t)(q3 & 0x1FFFFu) * H2_DIM + f];
            a0 += b2f(v0); a1 += b2f(v1); a2 += b2f(v2); a3 += b2f(v3);
        }
        for (; e < r1; ++e)
            a0 += b2f(in[(size_t)(sbuf[e] & 0x1FFFFu) * H2_DIM + f]);
        float acc = (a0 + a1) + (a2 + a3);
        int node = b * NPB + sl;
        if (node < N_NODES) {
            if (ROUND == 1) {
                z1b[(size_t)node * H2_DIM + f] = f2b(acc);
            } else {
                float v = acc + (float)(r1 - r0) * cf + bb;
                m = fmaxf(m, v);
            }
        }
    }
    if (ROUND == 2) {
        sm[t] = m;
        __syncthreads();
        if (g == 0) {
#pragma unroll
            for (int k = 1; k < 8; ++k) m = fmaxf(m, sm[k * 32 + f]);
            atomicMax(&pk[f], f32_to_key(m));
        }
    }
}

// ---------------- out = pooled @ Wf^T + bf ----------------
__global__ void final_kernel(const unsigned* __restrict__ pk,
                             const float* __restrict__ Wf,
                             const float* __restrict__ bfv,
                             float* __restrict__ out) {
    __shared__ float pooled[H2_DIM];
    int t = threadIdx.x;
    if (t < H2_DIM) {
        unsigned k = pk[t];
        unsigned u = (k & 0x80000000u) ? (k & 0x7FFFFFFFu) : ~k;
        pooled[t] = __uint_as_float(u);
    }
    __syncthreads();
    if (t < OUT_DIM) {
        float acc = bfv[t];
        for (int j = 0; j < H2_DIM; ++j)
            acc += Wf[t * H2_DIM + j] * pooled[j];
        out[t] = acc;
    }
}

extern "C" void kernel_launch(void* const* d_in, const int* in_sizes, int n_in,
                              void* d_out, int out_size, void* d_ws, size_t ws_size,
                              hipStream_t stream) {
    const float* x  = (const float*)d_in[0];
    const int*   ei = (const int*)d_in[1];           // [2, E]: row0 = src, row1 = dst
    const float* W1 = (const float*)d_in[2];
    const float* b1 = (const float*)d_in[3];
    const float* W2 = (const float*)d_in[4];
    const float* b2 = (const float*)d_in[5];
    const float* Wf = (const float*)d_in[6];
    const float* bf = (const float*)d_in[7];
    float* out = (float*)d_out;

    const int* src = ei;
    const int* dst = ei + N_EDGES;

    // workspace carve-up (~30 MB)
    unsigned short* yb  = (unsigned short*)d_ws;                 // N*32 bf16
    unsigned short* z1b = yb + (size_t)N_NODES * H2_DIM;         // N*32 bf16
    float* Wc   = (float*)(z1b + (size_t)N_NODES * H2_DIM);      // 32*128
    float* cvec = Wc + H2_DIM * IN_DIM;                          // 32
    unsigned* pk    = (unsigned*)(cvec + H2_DIM);                // 32
    unsigned* off   = pk + H2_DIM;                               // NCH*OFFW
    unsigned* grec  = off + (size_t)NCH * OFFW;                  // N_EDGES
    unsigned* grec2 = grec + N_EDGES;                            // KB*CAP2
    unsigned* noff  = grec2 + (size_t)KB * CAP2;                 // KB*65

    hipMemsetAsync(pk, 0, H2_DIM * sizeof(unsigned), stream);

    prep_kernel<<<1, 256, 0, stream>>>(W1, b1, W2, Wc, cvec);
    gemmy_kernel<<<(N_NODES + 7) / 8, 256, 0, stream>>>(x, Wc, yb);
    bin_kernel<<<NCH, 512, 0, stream>>>(src, dst, off, grec);

    agg_kernel<1><<<KB, 256, 0, stream>>>(yb, off, grec, grec2, noff, z1b, cvec, b2, pk);
    agg_kernel<2><<<KB, 256, 0, stream>>>(z1b, off, grec, grec2, noff, nullptr, cvec, b2, pk);

    final_kernel<<<1, 64, 0, stream>>>(pk, Wf, bf, out);
}

// Round 5
// 154.077 us; speedup vs baseline: 6.1576x; 1.2532x over previous
//
#include <hip/hip_runtime.h>

#define N_NODES 100000
#define N_EDGES 1600000
#define IN_DIM 128
#define H1_DIM 64
#define H2_DIM 32
#define OUT_DIM 16

#define NPB 64                       // src-nodes per bucket
#define KB 1563                      // ceil(N_NODES / NPB)
#define OFFW (KB + 1)                // off-table row width (with sentinel)
#define NCH 128                      // edge chunks (private regions)
#define CH_E (N_EDGES / NCH)         // 12500 edges per chunk (exact)
#define CAP2 1536                    // per-bucket record cap (mean 1024, +16 sigma)

typedef __attribute__((ext_vector_type(8))) short short8;
typedef __attribute__((ext_vector_type(4))) float f32x4;

// ---------------- helpers ----------------
__device__ inline float b2f(unsigned short h) {
    return __uint_as_float(((unsigned)h) << 16);
}
__device__ inline unsigned short f2b(float v) {   // RNE f32 -> bf16
    unsigned u = __float_as_uint(v);
    u += 0x7FFF + ((u >> 16) & 1);
    return (unsigned short)(u >> 16);
}
__device__ inline short f2bs(float v) { return (short)f2b(v); }
__device__ inline unsigned f32_to_key(float v) {
    unsigned u = __float_as_uint(v);
    return (v >= 0.f) ? (u | 0x80000000u) : ~u;
}

// ---------------- prep: Wcb = bf16(W2@W1) [32x128], cvec = W2@b1 [32] ---------
__global__ void prep_kernel(const float* __restrict__ W1, const float* __restrict__ b1,
                            const float* __restrict__ W2,
                            unsigned short* __restrict__ Wcb, float* __restrict__ cvec) {
    int t = threadIdx.x;  // 256 threads, 1 block
    for (int idx = t; idx < H2_DIM * IN_DIM; idx += 256) {
        int j = idx >> 7, f = idx & 127;
        float acc = 0.f;
        for (int k = 0; k < H1_DIM; ++k)
            acc += W2[j * H1_DIM + k] * W1[k * IN_DIM + f];
        Wcb[idx] = f2b(acc);
    }
    if (t < H2_DIM) {
        float acc = 0.f;
        for (int k = 0; k < H1_DIM; ++k)
            acc += W2[t * H1_DIM + k] * b1[k];
        cvec[t] = acc;
    }
}

// ---------------- y = x @ Wc^T  [N,32] -> bf16, via MFMA ----------------
// Wave handles 16 nodes x 32 outputs: two 16x16 C-tiles, K=128 in 4 steps.
// A frag: lane l holds row (l&15), k = 32*kk + 8*(l>>4) + e  (8 fp32 -> bf16)
// B frag: lane l holds col (l&15), same k-slice; B[k][n] = Wc[n][k] (row-major 16B)
// C frag: col = l&15, row = (l>>4)*4 + r   [m89-verified]
__global__ __launch_bounds__(256) void gemmy_kernel(const float* __restrict__ x,
                                                    const unsigned short* __restrict__ Wcb,
                                                    unsigned short* __restrict__ yb) {
    int t = threadIdx.x;
    int w = t >> 6, l = t & 63;
    int row = l & 15, kg = l >> 4;          // kg in 0..3
    int base = blockIdx.x * 64 + w * 16;
    int node = base + row;
    int nclamp = (node < N_NODES) ? node : (N_NODES - 1);
    const float* xp = x + (size_t)nclamp * IN_DIM + kg * 8;
    const unsigned short* b0p = Wcb + (size_t)row * IN_DIM + kg * 8;
    const unsigned short* b1p = Wcb + (size_t)(16 + row) * IN_DIM + kg * 8;
    f32x4 acc0 = {0.f, 0.f, 0.f, 0.f}, acc1 = {0.f, 0.f, 0.f, 0.f};
#pragma unroll
    for (int kk = 0; kk < 4; ++kk) {
        float4 xa = *(const float4*)(xp + kk * 32);
        float4 xb = *(const float4*)(xp + kk * 32 + 4);
        short8 a;
        a[0] = f2bs(xa.x); a[1] = f2bs(xa.y); a[2] = f2bs(xa.z); a[3] = f2bs(xa.w);
        a[4] = f2bs(xb.x); a[5] = f2bs(xb.y); a[6] = f2bs(xb.z); a[7] = f2bs(xb.w);
        short8 b0 = *(const short8*)(b0p + kk * 32);
        short8 b1 = *(const short8*)(b1p + kk * 32);
        acc0 = __builtin_amdgcn_mfma_f32_16x16x32_bf16(a, b0, acc0, 0, 0, 0);
        acc1 = __builtin_amdgcn_mfma_f32_16x16x32_bf16(a, b1, acc1, 0, 0, 0);
    }
#pragma unroll
    for (int r = 0; r < 4; ++r) {
        int n2 = base + kg * 4 + r;
        if (n2 < N_NODES) {
            yb[(size_t)n2 * H2_DIM + row]      = f2b(acc0[r]);
            yb[(size_t)n2 * H2_DIM + 16 + row] = f2b(acc1[r]);
        }
    }
}

// ---------------- bin: chunk-private bucket binning ---------------------------
__global__ __launch_bounds__(512) void bin_kernel(const int* __restrict__ src,
                                                  const int* __restrict__ dst,
                                                  unsigned* __restrict__ off,
                                                  unsigned* __restrict__ grec) {
    __shared__ int hist[2048];
    __shared__ int part[512];
    __shared__ int cur[2048];
    int t = threadIdx.x;
    int c = blockIdx.x;
    int e0 = c * CH_E;

    for (int i = t; i < 2048; i += 512) hist[i] = 0;
    __syncthreads();
    for (int e = t; e < CH_E; e += 512) {
        int s = src[e0 + e];
        atomicAdd(&hist[s >> 6], 1);
    }
    __syncthreads();
    int h0 = hist[4 * t], h1 = hist[4 * t + 1], h2 = hist[4 * t + 2], h3 = hist[4 * t + 3];
    int tot = h0 + h1 + h2 + h3;
    part[t] = tot;
    __syncthreads();
    for (int o = 1; o < 512; o <<= 1) {
        int a = (t >= o) ? part[t - o] : 0;
        __syncthreads();
        part[t] += a;
        __syncthreads();
    }
    int gb = part[t] - tot;  // exclusive prefix of this 4-group
    int o0 = gb, o1 = gb + h0, o2 = o1 + h1, o3 = o2 + h2;
    int b4 = 4 * t;
    if (b4 + 0 < KB) { off[(size_t)c * OFFW + b4 + 0] = o0; cur[b4 + 0] = o0; }
    if (b4 + 1 < KB) { off[(size_t)c * OFFW + b4 + 1] = o1; cur[b4 + 1] = o1; }
    if (b4 + 2 < KB) { off[(size_t)c * OFFW + b4 + 2] = o2; cur[b4 + 2] = o2; }
    if (b4 + 3 < KB) { off[(size_t)c * OFFW + b4 + 3] = o3; cur[b4 + 3] = o3; }
    if (t == 0) off[(size_t)c * OFFW + KB] = CH_E;   // sentinel
    __syncthreads();
    for (int e = t; e < CH_E; e += 512) {
        int s = src[e0 + e];
        int d = dst[e0 + e];
        int p = atomicAdd(&cur[s >> 6], 1);
        grec[(size_t)e0 + p] = ((unsigned)(s & 63) << 17) | (unsigned)d;
    }
}

// ---------------- agg: per-bucket node-sorted register-accum gather -----------
template <int ROUND>
__global__ __launch_bounds__(256) void agg_kernel(const unsigned short* __restrict__ in,
                                                  const unsigned* __restrict__ off,
                                                  const unsigned* __restrict__ grec,
                                                  unsigned* __restrict__ grec2,
                                                  unsigned* __restrict__ noff,
                                                  unsigned short* __restrict__ z1b,
                                                  const float* __restrict__ cvec,
                                                  const float* __restrict__ b2,
                                                  unsigned* __restrict__ pk) {
    __shared__ int len[128], pos[128], sst[128];
    __shared__ int shist[64], scur[64];
    __shared__ int sscan[65];
    __shared__ unsigned rbuf[CAP2];
    __shared__ unsigned sbuf[CAP2];
    __shared__ float sm[256];
    __shared__ int s_cnt;
    int t = threadIdx.x;
    int b = blockIdx.x;
    int g = t >> 5, f = t & 31;

    if (ROUND == 1) {
        if (t < 128) {
            unsigned o0 = off[(size_t)t * OFFW + b];
            unsigned o1 = off[(size_t)t * OFFW + b + 1];
            sst[t] = (int)o0;
            len[t] = (int)(o1 - o0);
            pos[t] = (int)(o1 - o0);
        }
        __syncthreads();
        for (int o = 1; o < 128; o <<= 1) {
            int a = (t < 128 && t >= o) ? pos[t - o] : 0;
            __syncthreads();
            if (t < 128) pos[t] += a;
            __syncthreads();
        }
        if (t < 128) pos[t] -= len[t];              // exclusive
        if (t == 127) s_cnt = min(pos[127] + len[127], CAP2);
        __syncthreads();
        for (int c = g; c < 128; c += 8) {
            int L = len[c], P = pos[c], S = sst[c];
            for (int k = f; k < L; k += 32) {
                int q = P + k;
                if (q < CAP2) rbuf[q] = grec[(size_t)c * CH_E + S + k];
            }
        }
        if (t < 64) shist[t] = 0;
        __syncthreads();
        int cnt = s_cnt;
        for (int i = t; i < cnt; i += 256) atomicAdd(&shist[rbuf[i] >> 17], 1);
        __syncthreads();
        if (t < 64) scur[t] = shist[t];
        __syncthreads();
        for (int o = 1; o < 64; o <<= 1) {
            int a = (t < 64 && t >= o) ? scur[t - o] : 0;
            __syncthreads();
            if (t < 64) scur[t] += a;
            __syncthreads();
        }
        if (t < 64) sscan[t] = scur[t] - shist[t];
        if (t == 63) sscan[64] = scur[63];
        __syncthreads();
        if (t < 64) scur[t] = sscan[t];
        __syncthreads();
        for (int i = t; i < cnt; i += 256) {
            unsigned r = rbuf[i];
            int p = atomicAdd(&scur[r >> 17], 1);
            if (p < CAP2) sbuf[p] = r;
        }
        __syncthreads();
        for (int i = t; i < cnt; i += 256) grec2[(size_t)b * CAP2 + i] = sbuf[i];
        if (t < 65) noff[(size_t)b * 65 + t] = (unsigned)sscan[t];
    } else {
        if (t < 65) sscan[t] = (int)noff[(size_t)b * 65 + t];
        __syncthreads();
        int cnt = sscan[64];
        for (int i = t; i < cnt; i += 256) sbuf[i] = grec2[(size_t)b * CAP2 + i];
    }
    __syncthreads();

    float cf = 0.f, bb = 0.f, m = -3.402823466e+38f;
    if (ROUND == 2) { cf = cvec[f]; bb = b2[f]; }
    for (int sl = g; sl < 64; sl += 8) {
        int r0 = sscan[sl], r1 = sscan[sl + 1];
        float a0 = 0.f, a1 = 0.f, a2 = 0.f, a3 = 0.f;
        int e = r0;
        for (; e + 4 <= r1; e += 4) {
            unsigned q0 = sbuf[e], q1 = sbuf[e + 1], q2 = sbuf[e + 2], q3 = sbuf[e + 3];
            unsigned short v0 = in[(size_t)(q0 & 0x1FFFFu) * H2_DIM + f];
            unsigned short v1 = in[(size_t)(q1 & 0x1FFFFu) * H2_DIM + f];
            unsigned short v2 = in[(size_t)(q2 & 0x1FFFFu) * H2_DIM + f];
            unsigned short v3 = in[(size_t)(q3 & 0x1FFFFu) * H2_DIM + f];
            a0 += b2f(v0); a1 += b2f(v1); a2 += b2f(v2); a3 += b2f(v3);
        }
        for (; e < r1; ++e)
            a0 += b2f(in[(size_t)(sbuf[e] & 0x1FFFFu) * H2_DIM + f]);
        float acc = (a0 + a1) + (a2 + a3);
        int node = b * NPB + sl;
        if (node < N_NODES) {
            if (ROUND == 1) {
                z1b[(size_t)node * H2_DIM + f] = f2b(acc);
            } else {
                float v = acc + (float)(r1 - r0) * cf + bb;
                m = fmaxf(m, v);
            }
        }
    }
    if (ROUND == 2) {
        sm[t] = m;
        __syncthreads();
        if (g == 0) {
#pragma unroll
            for (int k = 1; k < 8; ++k) m = fmaxf(m, sm[k * 32 + f]);
            atomicMax(&pk[f], f32_to_key(m));
        }
    }
}

// ---------------- out = pooled @ Wf^T + bf ----------------
__global__ void final_kernel(const unsigned* __restrict__ pk,
                             const float* __restrict__ Wf,
                             const float* __restrict__ bfv,
                             float* __restrict__ out) {
    __shared__ float pooled[H2_DIM];
    int t = threadIdx.x;
    if (t < H2_DIM) {
        unsigned k = pk[t];
        unsigned u = (k & 0x80000000u) ? (k & 0x7FFFFFFFu) : ~k;
        pooled[t] = __uint_as_float(u);
    }
    __syncthreads();
    if (t < OUT_DIM) {
        float acc = bfv[t];
        for (int j = 0; j < H2_DIM; ++j)
            acc += Wf[t * H2_DIM + j] * pooled[j];
        out[t] = acc;
    }
}

extern "C" void kernel_launch(void* const* d_in, const int* in_sizes, int n_in,
                              void* d_out, int out_size, void* d_ws, size_t ws_size,
                              hipStream_t stream) {
    const float* x  = (const float*)d_in[0];
    const int*   ei = (const int*)d_in[1];           // [2, E]: row0 = src, row1 = dst
    const float* W1 = (const float*)d_in[2];
    const float* b1 = (const float*)d_in[3];
    const float* W2 = (const float*)d_in[4];
    const float* b2 = (const float*)d_in[5];
    const float* Wf = (const float*)d_in[6];
    const float* bf = (const float*)d_in[7];
    float* out = (float*)d_out;

    const int* src = ei;
    const int* dst = ei + N_EDGES;

    // workspace carve-up (~30 MB)
    unsigned short* yb  = (unsigned short*)d_ws;                 // N*32 bf16
    unsigned short* z1b = yb + (size_t)N_NODES * H2_DIM;         // N*32 bf16
    unsigned short* Wcb = z1b + (size_t)N_NODES * H2_DIM;        // 32*128 bf16
    float* cvec = (float*)(Wcb + H2_DIM * IN_DIM);               // 32
    unsigned* pk    = (unsigned*)(cvec + H2_DIM);                // 32
    unsigned* off   = pk + H2_DIM;                               // NCH*OFFW
    unsigned* grec  = off + (size_t)NCH * OFFW;                  // N_EDGES
    unsigned* grec2 = grec + N_EDGES;                            // KB*CAP2
    unsigned* noff  = grec2 + (size_t)KB * CAP2;                 // KB*65

    hipMemsetAsync(pk, 0, H2_DIM * sizeof(unsigned), stream);

    prep_kernel<<<1, 256, 0, stream>>>(W1, b1, W2, Wcb, cvec);
    gemmy_kernel<<<(N_NODES + 63) / 64, 256, 0, stream>>>(x, Wcb, yb);
    bin_kernel<<<NCH, 512, 0, stream>>>(src, dst, off, grec);

    agg_kernel<1><<<KB, 256, 0, stream>>>(yb, off, grec, grec2, noff, z1b, cvec, b2, pk);
    agg_kernel<2><<<KB, 256, 0, stream>>>(z1b, off, grec, grec2, noff, nullptr, cvec, b2, pk);

    final_kernel<<<1, 64, 0, stream>>>(pk, Wf, bf, out);
}

// Round 6
// 148.928 us; speedup vs baseline: 6.3706x; 1.0346x over previous
//
#include <hip/hip_runtime.h>

#define N_NODES 100000
#define N_EDGES 1600000
#define IN_DIM 128
#define H1_DIM 64
#define H2_DIM 32
#define OUT_DIM 16

#define NPB 64                       // src-nodes per bucket
#define KB 1563                      // ceil(N_NODES / NPB)
#define OFFW (KB + 1)                // off-table row width (with sentinel)
#define NCH 128                      // edge chunks (private regions)
#define CH_E (N_EDGES / NCH)         // 12500 edges per chunk (exact)
#define CAP2 1536                    // per-bucket record cap (mean 1024, +16 sigma)

typedef __attribute__((ext_vector_type(8))) short short8;
typedef __attribute__((ext_vector_type(4))) float f32x4;

// ---------------- helpers ----------------
__device__ inline float b2f(unsigned short h) {
    return __uint_as_float(((unsigned)h) << 16);
}
__device__ inline unsigned short f2b(float v) {   // RNE f32 -> bf16
    unsigned u = __float_as_uint(v);
    u += 0x7FFF + ((u >> 16) & 1);
    return (unsigned short)(u >> 16);
}
__device__ inline short f2bs(float v) { return (short)f2b(v); }
__device__ inline unsigned f32_to_key(float v) {
    unsigned u = __float_as_uint(v);
    return (v >= 0.f) ? (u | 0x80000000u) : ~u;
}

// ---------------- prep: Wcb = bf16(W2@W1) [32x128], cvec = W2@b1 [32] ---------
__global__ void prep_kernel(const float* __restrict__ W1, const float* __restrict__ b1,
                            const float* __restrict__ W2,
                            unsigned short* __restrict__ Wcb, float* __restrict__ cvec) {
    int t = threadIdx.x;  // 256 threads, 1 block
    for (int idx = t; idx < H2_DIM * IN_DIM; idx += 256) {
        int j = idx >> 7, f = idx & 127;
        float acc = 0.f;
        for (int k = 0; k < H1_DIM; ++k)
            acc += W2[j * H1_DIM + k] * W1[k * IN_DIM + f];
        Wcb[idx] = f2b(acc);
    }
    if (t < H2_DIM) {
        float acc = 0.f;
        for (int k = 0; k < H1_DIM; ++k)
            acc += W2[t * H1_DIM + k] * b1[k];
        cvec[t] = acc;
    }
}

// ---------------- y = x @ Wc^T  [N,32] -> bf16, via MFMA ----------------
__global__ __launch_bounds__(256) void gemmy_kernel(const float* __restrict__ x,
                                                    const unsigned short* __restrict__ Wcb,
                                                    unsigned short* __restrict__ yb) {
    int t = threadIdx.x;
    int w = t >> 6, l = t & 63;
    int row = l & 15, kg = l >> 4;          // kg in 0..3
    int base = blockIdx.x * 64 + w * 16;
    int node = base + row;
    int nclamp = (node < N_NODES) ? node : (N_NODES - 1);
    const float* xp = x + (size_t)nclamp * IN_DIM + kg * 8;
    const unsigned short* b0p = Wcb + (size_t)row * IN_DIM + kg * 8;
    const unsigned short* b1p = Wcb + (size_t)(16 + row) * IN_DIM + kg * 8;
    f32x4 acc0 = {0.f, 0.f, 0.f, 0.f}, acc1 = {0.f, 0.f, 0.f, 0.f};
#pragma unroll
    for (int kk = 0; kk < 4; ++kk) {
        float4 xa = *(const float4*)(xp + kk * 32);
        float4 xb = *(const float4*)(xp + kk * 32 + 4);
        short8 a;
        a[0] = f2bs(xa.x); a[1] = f2bs(xa.y); a[2] = f2bs(xa.z); a[3] = f2bs(xa.w);
        a[4] = f2bs(xb.x); a[5] = f2bs(xb.y); a[6] = f2bs(xb.z); a[7] = f2bs(xb.w);
        short8 b0 = *(const short8*)(b0p + kk * 32);
        short8 b1 = *(const short8*)(b1p + kk * 32);
        acc0 = __builtin_amdgcn_mfma_f32_16x16x32_bf16(a, b0, acc0, 0, 0, 0);
        acc1 = __builtin_amdgcn_mfma_f32_16x16x32_bf16(a, b1, acc1, 0, 0, 0);
    }
#pragma unroll
    for (int r = 0; r < 4; ++r) {
        int n2 = base + kg * 4 + r;
        if (n2 < N_NODES) {
            yb[(size_t)n2 * H2_DIM + row]      = f2b(acc0[r]);
            yb[(size_t)n2 * H2_DIM + 16 + row] = f2b(acc1[r]);
        }
    }
}

// ---------------- bin: chunk-private bucket binning ---------------------------
__global__ __launch_bounds__(512) void bin_kernel(const int* __restrict__ src,
                                                  const int* __restrict__ dst,
                                                  unsigned* __restrict__ off,
                                                  unsigned* __restrict__ grec) {
    __shared__ int hist[2048];
    __shared__ int part[512];
    __shared__ int cur[2048];
    int t = threadIdx.x;
    int c = blockIdx.x;
    int e0 = c * CH_E;

    for (int i = t; i < 2048; i += 512) hist[i] = 0;
    __syncthreads();
    for (int e = t; e < CH_E; e += 512) {
        int s = src[e0 + e];
        atomicAdd(&hist[s >> 6], 1);
    }
    __syncthreads();
    int h0 = hist[4 * t], h1 = hist[4 * t + 1], h2 = hist[4 * t + 2], h3 = hist[4 * t + 3];
    int tot = h0 + h1 + h2 + h3;
    part[t] = tot;
    __syncthreads();
    for (int o = 1; o < 512; o <<= 1) {
        int a = (t >= o) ? part[t - o] : 0;
        __syncthreads();
        part[t] += a;
        __syncthreads();
    }
    int gb = part[t] - tot;  // exclusive prefix of this 4-group
    int o0 = gb, o1 = gb + h0, o2 = o1 + h1, o3 = o2 + h2;
    int b4 = 4 * t;
    if (b4 + 0 < KB) { off[(size_t)c * OFFW + b4 + 0] = o0; cur[b4 + 0] = o0; }
    if (b4 + 1 < KB) { off[(size_t)c * OFFW + b4 + 1] = o1; cur[b4 + 1] = o1; }
    if (b4 + 2 < KB) { off[(size_t)c * OFFW + b4 + 2] = o2; cur[b4 + 2] = o2; }
    if (b4 + 3 < KB) { off[(size_t)c * OFFW + b4 + 3] = o3; cur[b4 + 3] = o3; }
    if (t == 0) off[(size_t)c * OFFW + KB] = CH_E;   // sentinel
    __syncthreads();
    for (int e = t; e < CH_E; e += 512) {
        int s = src[e0 + e];
        int d = dst[e0 + e];
        int p = atomicAdd(&cur[s >> 6], 1);
        grec[(size_t)e0 + p] = ((unsigned)(s & 63) << 17) | (unsigned)d;
    }
}

// ---------------- agg: per-bucket node-sorted quad-vectorized gather ----------
// Gather: 32-lane group per node; per iteration 8 records (2 quads).
// Lane L: chunk=(L&7) -> features [4c,4c+4), subset=(L>>3) -> record e+subset.
// uint2 load = 8B; shfl_xor(8,16) folds the 4 subsets.
template <int ROUND>
__global__ __launch_bounds__(256) void agg_kernel(const unsigned short* __restrict__ in,
                                                  const unsigned* __restrict__ off,
                                                  const unsigned* __restrict__ grec,
                                                  unsigned* __restrict__ grec2,
                                                  unsigned* __restrict__ noff,
                                                  unsigned short* __restrict__ z1b,
                                                  const float* __restrict__ cvec,
                                                  const float* __restrict__ b2,
                                                  unsigned* __restrict__ pk) {
    __shared__ int len[128], pos[128], sst[128];
    __shared__ int shist[64], scur[64];
    __shared__ int sscan[65];
    __shared__ unsigned rbuf[CAP2];
    __shared__ unsigned sbuf[CAP2];
    __shared__ float smq[8][8][4];
    __shared__ int s_cnt;
    int t = threadIdx.x;
    int b = blockIdx.x;
    int g = t >> 5, L = t & 31;
    int chunk = L & 7, subset = L >> 3;

    if (ROUND == 1) {
        if (t < 128) {
            unsigned o0 = off[(size_t)t * OFFW + b];
            unsigned o1 = off[(size_t)t * OFFW + b + 1];
            sst[t] = (int)o0;
            len[t] = (int)(o1 - o0);
            pos[t] = (int)(o1 - o0);
        }
        __syncthreads();
        for (int o = 1; o < 128; o <<= 1) {
            int a = (t < 128 && t >= o) ? pos[t - o] : 0;
            __syncthreads();
            if (t < 128) pos[t] += a;
            __syncthreads();
        }
        if (t < 128) pos[t] -= len[t];              // exclusive
        if (t == 127) s_cnt = min(pos[127] + len[127], CAP2);
        __syncthreads();
        for (int c = g; c < 128; c += 8) {
            int Ln = len[c], P = pos[c], S = sst[c];
            for (int k = L; k < Ln; k += 32) {
                int q = P + k;
                if (q < CAP2) rbuf[q] = grec[(size_t)c * CH_E + S + k];
            }
        }
        if (t < 64) shist[t] = 0;
        __syncthreads();
        int cnt = s_cnt;
        for (int i = t; i < cnt; i += 256) atomicAdd(&shist[rbuf[i] >> 17], 1);
        __syncthreads();
        if (t < 64) scur[t] = shist[t];
        __syncthreads();
        for (int o = 1; o < 64; o <<= 1) {
            int a = (t < 64 && t >= o) ? scur[t - o] : 0;
            __syncthreads();
            if (t < 64) scur[t] += a;
            __syncthreads();
        }
        if (t < 64) sscan[t] = scur[t] - shist[t];
        if (t == 63) sscan[64] = scur[63];
        __syncthreads();
        if (t < 64) scur[t] = sscan[t];
        __syncthreads();
        for (int i = t; i < cnt; i += 256) {
            unsigned r = rbuf[i];
            int p = atomicAdd(&scur[r >> 17], 1);
            if (p < CAP2) sbuf[p] = r;
        }
        __syncthreads();
        for (int i = t; i < cnt; i += 256) grec2[(size_t)b * CAP2 + i] = sbuf[i];
        if (t < 65) noff[(size_t)b * 65 + t] = (unsigned)sscan[t];
    } else {
        if (t < 65) sscan[t] = (int)noff[(size_t)b * 65 + t];
        __syncthreads();
        int cnt = sscan[64];
        for (int i = t; i < cnt; i += 256) sbuf[i] = grec2[(size_t)b * CAP2 + i];
    }
    __syncthreads();

    // per-lane feature constants (4 features each)
    float cf0 = 0.f, cf1 = 0.f, cf2 = 0.f, cf3 = 0.f;
    float bb0 = 0.f, bb1 = 0.f, bb2 = 0.f, bb3 = 0.f;
    float m0, m1, m2, m3;
    const float NEGINF = -3.402823466e+38f;
    m0 = m1 = m2 = m3 = NEGINF;
    if (ROUND == 2) {
        cf0 = cvec[4 * chunk];     cf1 = cvec[4 * chunk + 1];
        cf2 = cvec[4 * chunk + 2]; cf3 = cvec[4 * chunk + 3];
        bb0 = b2[4 * chunk];       bb1 = b2[4 * chunk + 1];
        bb2 = b2[4 * chunk + 2];   bb3 = b2[4 * chunk + 3];
    }

    for (int sl = g; sl < 64; sl += 8) {
        int r0 = sscan[sl], r1 = sscan[sl + 1];
        float a0 = 0.f, a1 = 0.f, a2 = 0.f, a3 = 0.f;
        float c0 = 0.f, c1 = 0.f, c2 = 0.f, c3 = 0.f;
        for (int e = r0; e < r1; e += 8) {
            int eA = e + subset, eB = e + 4 + subset;
            if (eA < r1) {
                unsigned rc = sbuf[eA];
                const uint2* p = (const uint2*)(in + (size_t)(rc & 0x1FFFFu) * H2_DIM + chunk * 4);
                uint2 v = *p;
                a0 += __uint_as_float(v.x << 16);
                a1 += __uint_as_float(v.x & 0xFFFF0000u);
                a2 += __uint_as_float(v.y << 16);
                a3 += __uint_as_float(v.y & 0xFFFF0000u);
            }
            if (eB < r1) {
                unsigned rc = sbuf[eB];
                const uint2* p = (const uint2*)(in + (size_t)(rc & 0x1FFFFu) * H2_DIM + chunk * 4);
                uint2 v = *p;
                c0 += __uint_as_float(v.x << 16);
                c1 += __uint_as_float(v.x & 0xFFFF0000u);
                c2 += __uint_as_float(v.y << 16);
                c3 += __uint_as_float(v.y & 0xFFFF0000u);
            }
        }
        a0 += c0; a1 += c1; a2 += c2; a3 += c3;
        // fold the 4 record-subsets (masks 8 and 16 stay within the 32-lane group)
        a0 += __shfl_xor(a0, 8);  a1 += __shfl_xor(a1, 8);
        a2 += __shfl_xor(a2, 8);  a3 += __shfl_xor(a3, 8);
        a0 += __shfl_xor(a0, 16); a1 += __shfl_xor(a1, 16);
        a2 += __shfl_xor(a2, 16); a3 += __shfl_xor(a3, 16);
        int node = b * NPB + sl;
        if (node < N_NODES) {
            if (ROUND == 1) {
                if (subset == 0) {
                    uint2 o;
                    o.x = (unsigned)f2b(a0) | ((unsigned)f2b(a1) << 16);
                    o.y = (unsigned)f2b(a2) | ((unsigned)f2b(a3) << 16);
                    *(uint2*)(z1b + (size_t)node * H2_DIM + chunk * 4) = o;
                }
            } else {
                float dg = (float)(r1 - r0);
                m0 = fmaxf(m0, a0 + dg * cf0 + bb0);
                m1 = fmaxf(m1, a1 + dg * cf1 + bb1);
                m2 = fmaxf(m2, a2 + dg * cf2 + bb2);
                m3 = fmaxf(m3, a3 + dg * cf3 + bb3);
            }
        }
    }
    if (ROUND == 2) {
        if (subset == 0) {
            smq[g][chunk][0] = m0; smq[g][chunk][1] = m1;
            smq[g][chunk][2] = m2; smq[g][chunk][3] = m3;
        }
        __syncthreads();
        if (t < 32) {
            float m = smq[0][t >> 2][t & 3];
#pragma unroll
            for (int k = 1; k < 8; ++k) m = fmaxf(m, smq[k][t >> 2][t & 3]);
            atomicMax(&pk[t], f32_to_key(m));
        }
    }
}

// ---------------- out = pooled @ Wf^T + bf ----------------
__global__ void final_kernel(const unsigned* __restrict__ pk,
                             const float* __restrict__ Wf,
                             const float* __restrict__ bfv,
                             float* __restrict__ out) {
    __shared__ float pooled[H2_DIM];
    int t = threadIdx.x;
    if (t < H2_DIM) {
        unsigned k = pk[t];
        unsigned u = (k & 0x80000000u) ? (k & 0x7FFFFFFFu) : ~k;
        pooled[t] = __uint_as_float(u);
    }
    __syncthreads();
    if (t < OUT_DIM) {
        float acc = bfv[t];
        for (int j = 0; j < H2_DIM; ++j)
            acc += Wf[t * H2_DIM + j] * pooled[j];
        out[t] = acc;
    }
}

extern "C" void kernel_launch(void* const* d_in, const int* in_sizes, int n_in,
                              void* d_out, int out_size, void* d_ws, size_t ws_size,
                              hipStream_t stream) {
    const float* x  = (const float*)d_in[0];
    const int*   ei = (const int*)d_in[1];           // [2, E]: row0 = src, row1 = dst
    const float* W1 = (const float*)d_in[2];
    const float* b1 = (const float*)d_in[3];
    const float* W2 = (const float*)d_in[4];
    const float* b2 = (const float*)d_in[5];
    const float* Wf = (const float*)d_in[6];
    const float* bf = (const float*)d_in[7];
    float* out = (float*)d_out;

    const int* src = ei;
    const int* dst = ei + N_EDGES;

    // workspace carve-up (~30 MB)
    unsigned short* yb  = (unsigned short*)d_ws;                 // N*32 bf16
    unsigned short* z1b = yb + (size_t)N_NODES * H2_DIM;         // N*32 bf16
    unsigned short* Wcb = z1b + (size_t)N_NODES * H2_DIM;        // 32*128 bf16
    float* cvec = (float*)(Wcb + H2_DIM * IN_DIM);               // 32
    unsigned* pk    = (unsigned*)(cvec + H2_DIM);                // 32
    unsigned* off   = pk + H2_DIM;                               // NCH*OFFW
    unsigned* grec  = off + (size_t)NCH * OFFW;                  // N_EDGES
    unsigned* grec2 = grec + N_EDGES;                            // KB*CAP2
    unsigned* noff  = grec2 + (size_t)KB * CAP2;                 // KB*65

    hipMemsetAsync(pk, 0, H2_DIM * sizeof(unsigned), stream);

    prep_kernel<<<1, 256, 0, stream>>>(W1, b1, W2, Wcb, cvec);
    gemmy_kernel<<<(N_NODES + 63) / 64, 256, 0, stream>>>(x, Wcb, yb);
    bin_kernel<<<NCH, 512, 0, stream>>>(src, dst, off, grec);

    agg_kernel<1><<<KB, 256, 0, stream>>>(yb, off, grec, grec2, noff, z1b, cvec, b2, pk);
    agg_kernel<2><<<KB, 256, 0, stream>>>(z1b, off, grec, grec2, noff, nullptr, cvec, b2, pk);

    final_kernel<<<1, 64, 0, stream>>>(pk, Wf, bf, out);
}

// Round 7
// 118.585 us; speedup vs baseline: 8.0006x; 1.2559x over previous
//
#include <hip/hip_runtime.h>

#define N_NODES 100000
#define N_EDGES 1600000
#define IN_DIM 128
#define H1_DIM 64
#define H2_DIM 32
#define OUT_DIM 16

#define NPB 64                       // src-nodes per bucket
#define KB 1563                      // ceil(N_NODES / NPB)
#define OFFW (KB + 1)                // off-table row width (with sentinel)
#define NCH 256                      // edge chunks (private regions)
#define CH_E (N_EDGES / NCH)         // 6250 edges per chunk (exact)
#define CAP2 1536                    // per-bucket record cap (mean 1024, +16 sigma)
#define NBIN1 64                     // bin chunks done in K1 (with prep)
#define NBIN2 (NCH - NBIN1)          // bin chunks done in K2 (with gemmy)
#define NGB 782                      // ceil(N_NODES / 128) gemmy blocks

typedef __attribute__((ext_vector_type(8))) short short8;
typedef __attribute__((ext_vector_type(4))) float f32x4;

// ---------------- helpers ----------------
__device__ inline unsigned short f2b(float v) {   // RNE f32 -> bf16
    unsigned u = __float_as_uint(v);
    u += 0x7FFF + ((u >> 16) & 1);
    return (unsigned short)(u >> 16);
}
__device__ inline short f2bs(float v) { return (short)f2b(v); }
__device__ inline unsigned f32_to_key(float v) {
    unsigned u = __float_as_uint(v);
    return (v >= 0.f) ? (u | 0x80000000u) : ~u;
}
__device__ __forceinline__ void acc8(float* a, uint4 v) {
    a[0] += __uint_as_float(v.x << 16);
    a[1] += __uint_as_float(v.x & 0xFFFF0000u);
    a[2] += __uint_as_float(v.y << 16);
    a[3] += __uint_as_float(v.y & 0xFFFF0000u);
    a[4] += __uint_as_float(v.z << 16);
    a[5] += __uint_as_float(v.z & 0xFFFF0000u);
    a[6] += __uint_as_float(v.w << 16);
    a[7] += __uint_as_float(v.w & 0xFFFF0000u);
}

// ---------------- bin chunk (shared by K1/K2): 512 threads ----------------
__device__ __forceinline__ void bin_chunk(const int* __restrict__ src,
                                          const int* __restrict__ dst,
                                          unsigned* __restrict__ off,
                                          unsigned* __restrict__ grec, int c) {
    __shared__ int hist[2048];
    __shared__ int part[512];
    __shared__ int cur[2048];
    int t = threadIdx.x;
    int e0 = c * CH_E;
    for (int i = t; i < 2048; i += 512) hist[i] = 0;
    __syncthreads();
    for (int e = t; e < CH_E; e += 512) atomicAdd(&hist[src[e0 + e] >> 6], 1);
    __syncthreads();
    int h0 = hist[4 * t], h1 = hist[4 * t + 1], h2 = hist[4 * t + 2], h3 = hist[4 * t + 3];
    int tot = h0 + h1 + h2 + h3;
    part[t] = tot;
    __syncthreads();
    for (int o = 1; o < 512; o <<= 1) {
        int a = (t >= o) ? part[t - o] : 0;
        __syncthreads();
        part[t] += a;
        __syncthreads();
    }
    int gb = part[t] - tot;
    int o0 = gb, o1 = gb + h0, o2 = o1 + h1, o3 = o2 + h2;
    int b4 = 4 * t;
    cur[b4] = o0; cur[b4 + 1] = o1; cur[b4 + 2] = o2; cur[b4 + 3] = o3;
    if (b4 + 0 < KB) off[(size_t)c * OFFW + b4 + 0] = o0;
    if (b4 + 1 < KB) off[(size_t)c * OFFW + b4 + 1] = o1;
    if (b4 + 2 < KB) off[(size_t)c * OFFW + b4 + 2] = o2;
    if (b4 + 3 < KB) off[(size_t)c * OFFW + b4 + 3] = o3;
    if (t == 0) off[(size_t)c * OFFW + KB] = CH_E;   // sentinel
    __syncthreads();
    for (int e = t; e < CH_E; e += 512) {
        int s = src[e0 + e];
        int d = dst[e0 + e];
        int p = atomicAdd(&cur[s >> 6], 1);
        grec[(size_t)e0 + p] = ((unsigned)(s & 63) << 17) | (unsigned)d;
    }
}

// ---------------- K1: bin chunks 0..NBIN1-1  ||  prep (Wcb = bf16(W2@W1)) -----
__global__ __launch_bounds__(512) void k1_kernel(const int* __restrict__ src,
                                                 const int* __restrict__ dst,
                                                 unsigned* __restrict__ off,
                                                 unsigned* __restrict__ grec,
                                                 const float* __restrict__ W1,
                                                 const float* __restrict__ W2,
                                                 unsigned short* __restrict__ Wcb) {
    if (blockIdx.x < NBIN1) {
        bin_chunk(src, dst, off, grec, blockIdx.x);
        return;
    }
    int t = threadIdx.x;
    for (int idx = t; idx < H2_DIM * IN_DIM; idx += 512) {
        int j = idx >> 7, f = idx & 127;
        float acc = 0.f;
        for (int k = 0; k < H1_DIM; ++k)
            acc += W2[j * H1_DIM + k] * W1[k * IN_DIM + f];
        Wcb[idx] = f2b(acc);
    }
}

// ---------------- K2: bin chunks NBIN1..NCH-1  ||  gemmy (y = x@Wc^T, MFMA) ---
__global__ __launch_bounds__(512) void k2_kernel(const int* __restrict__ src,
                                                 const int* __restrict__ dst,
                                                 unsigned* __restrict__ off,
                                                 unsigned* __restrict__ grec,
                                                 const float* __restrict__ x,
                                                 const unsigned short* __restrict__ Wcb,
                                                 unsigned short* __restrict__ yb) {
    if (blockIdx.x < NBIN2) {
        bin_chunk(src, dst, off, grec, NBIN1 + blockIdx.x);
        return;
    }
    int gb = blockIdx.x - NBIN2;
    int t = threadIdx.x;
    int w = t >> 6, l = t & 63;
    int row = l & 15, kg = l >> 4;          // kg in 0..3
    int base = gb * 128 + w * 16;
    int node = base + row;
    int nclamp = (node < N_NODES) ? node : (N_NODES - 1);
    const float* xp = x + (size_t)nclamp * IN_DIM + kg * 8;
    const unsigned short* b0p = Wcb + (size_t)row * IN_DIM + kg * 8;
    const unsigned short* b1p = Wcb + (size_t)(16 + row) * IN_DIM + kg * 8;
    f32x4 acc0 = {0.f, 0.f, 0.f, 0.f}, acc1 = {0.f, 0.f, 0.f, 0.f};
#pragma unroll
    for (int kk = 0; kk < 4; ++kk) {
        float4 xa = *(const float4*)(xp + kk * 32);
        float4 xb = *(const float4*)(xp + kk * 32 + 4);
        short8 a;
        a[0] = f2bs(xa.x); a[1] = f2bs(xa.y); a[2] = f2bs(xa.z); a[3] = f2bs(xa.w);
        a[4] = f2bs(xb.x); a[5] = f2bs(xb.y); a[6] = f2bs(xb.z); a[7] = f2bs(xb.w);
        short8 b0 = *(const short8*)(b0p + kk * 32);
        short8 b1 = *(const short8*)(b1p + kk * 32);
        acc0 = __builtin_amdgcn_mfma_f32_16x16x32_bf16(a, b0, acc0, 0, 0, 0);
        acc1 = __builtin_amdgcn_mfma_f32_16x16x32_bf16(a, b1, acc1, 0, 0, 0);
    }
#pragma unroll
    for (int r = 0; r < 4; ++r) {
        int n2 = base + kg * 4 + r;
        if (n2 < N_NODES) {
            yb[(size_t)n2 * H2_DIM + row]      = f2b(acc0[r]);
            yb[(size_t)n2 * H2_DIM + 16 + row] = f2b(acc1[r]);
        }
    }
}

// ---------------- agg: 16-lane groups, uint4 gather, 4 chains/wave ------------
// Lane in group: chunk=L&3 (features 8c..8c+7, 16B), subset=L>>2 (record e+subset).
// Per node: 8 records per loop iter (2 quads in flight); shfl_xor(4,8) folds.
template <int ROUND>
__global__ __launch_bounds__(256) void agg_kernel(const unsigned short* __restrict__ in,
                                                  const unsigned* __restrict__ off,
                                                  const unsigned* __restrict__ grec,
                                                  unsigned* __restrict__ grec2,
                                                  unsigned* __restrict__ noff,
                                                  unsigned short* __restrict__ z1b,
                                                  const float* __restrict__ W2,
                                                  const float* __restrict__ b1,
                                                  const float* __restrict__ b2,
                                                  unsigned* __restrict__ pk) {
    __shared__ int len[NCH], pos[NCH], sst[NCH];
    __shared__ int shist[64], scur2[64];
    __shared__ int sscan[65];
    __shared__ unsigned rbuf[CAP2];
    __shared__ unsigned sbuf[CAP2];
    __shared__ float smq[16][4][8];
    __shared__ float scv[32], sb2v[32];
    __shared__ int s_cnt;
    int t = threadIdx.x;
    int b = blockIdx.x;
    int gid = t >> 4;              // 16 groups of 16 lanes
    int L = t & 15;
    int chunk = L & 3, subset = L >> 2;

    if (ROUND == 1) {
        {   // region table + scan (NCH == blockDim)
            unsigned o0 = off[(size_t)t * OFFW + b];
            unsigned o1 = off[(size_t)t * OFFW + b + 1];
            sst[t] = (int)o0;
            len[t] = (int)(o1 - o0);
            pos[t] = (int)(o1 - o0);
        }
        __syncthreads();
        for (int o = 1; o < NCH; o <<= 1) {
            int a = (t >= o) ? pos[t - o] : 0;
            __syncthreads();
            pos[t] += a;
            __syncthreads();
        }
        pos[t] -= len[t];              // exclusive
        if (t == NCH - 1) s_cnt = min(pos[t] + len[t], CAP2);
        __syncthreads();
        for (int c = gid; c < NCH; c += 16) {
            int Ln = len[c], P = pos[c], S = sst[c];
            for (int k = L; k < Ln; k += 16) {
                int q = P + k;
                if (q < CAP2) rbuf[q] = grec[(size_t)c * CH_E + S + k];
            }
        }
        if (t < 64) shist[t] = 0;
        __syncthreads();
        int cnt = s_cnt;
        for (int i = t; i < cnt; i += 256) atomicAdd(&shist[rbuf[i] >> 17], 1);
        __syncthreads();
        if (t < 64) scur2[t] = shist[t];
        __syncthreads();
        for (int o = 1; o < 64; o <<= 1) {
            int a = (t < 64 && t >= o) ? scur2[t - o] : 0;
            __syncthreads();
            if (t < 64) scur2[t] += a;
            __syncthreads();
        }
        if (t < 64) sscan[t] = scur2[t] - shist[t];
        if (t == 63) sscan[64] = scur2[63];
        __syncthreads();
        if (t < 64) scur2[t] = sscan[t];
        __syncthreads();
        for (int i = t; i < cnt; i += 256) {
            unsigned r = rbuf[i];
            int p = atomicAdd(&scur2[r >> 17], 1);
            if (p < CAP2) sbuf[p] = r;
        }
        __syncthreads();
        for (int i = t; i < cnt; i += 256) grec2[(size_t)b * CAP2 + i] = sbuf[i];
        if (t < 65) noff[(size_t)b * 65 + t] = (unsigned)sscan[t];
    } else {
        if (t < 65) sscan[t] = (int)noff[(size_t)b * 65 + t];
        __syncthreads();
        int cnt = sscan[64];
        for (int i = t; i < cnt; i += 256) sbuf[i] = grec2[(size_t)b * CAP2 + i];
        if (t < 32) {                  // inline cvec = W2 @ b1
            float s = 0.f;
            for (int k = 0; k < H1_DIM; ++k) s += W2[t * H1_DIM + k] * b1[k];
            scv[t] = s;
            sb2v[t] = b2[t];
        }
    }
    __syncthreads();

    float cfv[8], bbv[8], m[8];
    if (ROUND == 2) {
#pragma unroll
        for (int j = 0; j < 8; ++j) {
            cfv[j] = scv[chunk * 8 + j];
            bbv[j] = sb2v[chunk * 8 + j];
            m[j] = -3.402823466e+38f;
        }
    }

    for (int sl = gid; sl < NPB; sl += 16) {
        int r0 = sscan[sl], r1 = sscan[sl + 1];
        float a[8] = {0.f, 0.f, 0.f, 0.f, 0.f, 0.f, 0.f, 0.f};
        float aa[8] = {0.f, 0.f, 0.f, 0.f, 0.f, 0.f, 0.f, 0.f};
        for (int e = r0; e < r1; e += 8) {
            int eA = e + subset, eB = e + 4 + subset;
            if (eA < r1) {
                unsigned rc = sbuf[eA];
                uint4 v = *(const uint4*)(in + (size_t)(rc & 0x1FFFFu) * H2_DIM + chunk * 8);
                acc8(a, v);
            }
            if (eB < r1) {
                unsigned rc = sbuf[eB];
                uint4 v = *(const uint4*)(in + (size_t)(rc & 0x1FFFFu) * H2_DIM + chunk * 8);
                acc8(aa, v);
            }
        }
#pragma unroll
        for (int j = 0; j < 8; ++j) {
            float s = a[j] + aa[j];
            s += __shfl_xor(s, 4);
            s += __shfl_xor(s, 8);
            a[j] = s;
        }
        int node = b * NPB + sl;
        if (node < N_NODES) {
            if (ROUND == 1) {
                if (subset == 0) {
                    uint4 o;
                    o.x = (unsigned)f2b(a[0]) | ((unsigned)f2b(a[1]) << 16);
                    o.y = (unsigned)f2b(a[2]) | ((unsigned)f2b(a[3]) << 16);
                    o.z = (unsigned)f2b(a[4]) | ((unsigned)f2b(a[5]) << 16);
                    o.w = (unsigned)f2b(a[6]) | ((unsigned)f2b(a[7]) << 16);
                    *(uint4*)(z1b + (size_t)node * H2_DIM + chunk * 8) = o;
                }
            } else {
                float dg = (float)(r1 - r0);
#pragma unroll
                for (int j = 0; j < 8; ++j)
                    m[j] = fmaxf(m[j], a[j] + dg * cfv[j] + bbv[j]);
            }
        }
    }
    if (ROUND == 2) {
        if (subset == 0) {
#pragma unroll
            for (int j = 0; j < 8; ++j) smq[gid][chunk][j] = m[j];
        }
        __syncthreads();
        if (t < 32) {                  // feature f == t
            int c = t >> 3, j = t & 7;
            float mm = smq[0][c][j];
#pragma unroll
            for (int k = 1; k < 16; ++k) mm = fmaxf(mm, smq[k][c][j]);
            atomicMax(&pk[t], f32_to_key(mm));
        }
    }
}

// ---------------- out = pooled @ Wf^T + bf ----------------
__global__ void final_kernel(const unsigned* __restrict__ pk,
                             const float* __restrict__ Wf,
                             const float* __restrict__ bfv,
                             float* __restrict__ out) {
    __shared__ float pooled[H2_DIM];
    int t = threadIdx.x;
    if (t < H2_DIM) {
        unsigned k = pk[t];
        unsigned u = (k & 0x80000000u) ? (k & 0x7FFFFFFFu) : ~k;
        pooled[t] = __uint_as_float(u);
    }
    __syncthreads();
    if (t < OUT_DIM) {
        float acc = bfv[t];
        for (int j = 0; j < H2_DIM; ++j)
            acc += Wf[t * H2_DIM + j] * pooled[j];
        out[t] = acc;
    }
}

extern "C" void kernel_launch(void* const* d_in, const int* in_sizes, int n_in,
                              void* d_out, int out_size, void* d_ws, size_t ws_size,
                              hipStream_t stream) {
    const float* x  = (const float*)d_in[0];
    const int*   ei = (const int*)d_in[1];           // [2, E]: row0 = src, row1 = dst
    const float* W1 = (const float*)d_in[2];
    const float* b1 = (const float*)d_in[3];
    const float* W2 = (const float*)d_in[4];
    const float* b2 = (const float*)d_in[5];
    const float* Wf = (const float*)d_in[6];
    const float* bf = (const float*)d_in[7];
    float* out = (float*)d_out;

    const int* src = ei;
    const int* dst = ei + N_EDGES;

    // workspace carve-up (~32 MB)
    unsigned short* yb  = (unsigned short*)d_ws;                 // N*32 bf16
    unsigned short* z1b = yb + (size_t)N_NODES * H2_DIM;         // N*32 bf16
    unsigned short* Wcb = z1b + (size_t)N_NODES * H2_DIM;        // 32*128 bf16
    unsigned* pk    = (unsigned*)(Wcb + H2_DIM * IN_DIM);        // 32
    unsigned* off   = pk + H2_DIM;                               // NCH*OFFW
    unsigned* grec  = off + (size_t)NCH * OFFW;                  // N_EDGES
    unsigned* grec2 = grec + N_EDGES;                            // KB*CAP2
    unsigned* noff  = grec2 + (size_t)KB * CAP2;                 // KB*65

    hipMemsetAsync(pk, 0, H2_DIM * sizeof(unsigned), stream);

    k1_kernel<<<NBIN1 + 1, 512, 0, stream>>>(src, dst, off, grec, W1, W2, Wcb);
    k2_kernel<<<NBIN2 + NGB, 512, 0, stream>>>(src, dst, off, grec, x, Wcb, yb);

    agg_kernel<1><<<KB, 256, 0, stream>>>(yb, off, grec, grec2, noff, z1b,
                                          nullptr, nullptr, nullptr, pk);
    agg_kernel<2><<<KB, 256, 0, stream>>>(z1b, off, grec, grec2, noff, nullptr,
                                          W2, b1, b2, pk);

    final_kernel<<<1, 64, 0, stream>>>(pk, Wf, bf, out);
}